// Round 2
// baseline (411.896 us; speedup 1.0000x reference)
//
#include <hip/hip_runtime.h>
#include <hip/hip_bf16.h>

#define EPS 1e-6f

typedef float f32x4 __attribute__((ext_vector_type(4)));
typedef short s16x8 __attribute__((ext_vector_type(8)));

__device__ __forceinline__ unsigned cvt2u(float x, float y) {
  __hip_bfloat162 h = __float22bfloat162_rn(make_float2(x, y));
  union { __hip_bfloat162 h; unsigned u; } c; c.h = h; return c.u;
}

__device__ __forceinline__ uint4 pack8(const f32x4 a, const f32x4 b) {
  uint4 r;
  r.x = cvt2u(a[0], a[1]); r.y = cvt2u(a[2], a[3]);
  r.z = cvt2u(b[0], b[1]); r.w = cvt2u(b[2], b[3]);
  return r;
}

__device__ __forceinline__ float bf2f(unsigned short u) {
  unsigned x = ((unsigned)u) << 16;
  union { unsigned u; float f; } c; c.u = x; return c.f;
}

// ---------------- kernel 1: per-centroid  csq + 2*eps*csum ----------------
__global__ __launch_bounds__(256) void centroid_stats(const float* __restrict__ C,
                                                      float* __restrict__ cterm) {
  const int wv = threadIdx.x >> 6, ln = threadIdx.x & 63;
  const int w = (blockIdx.x << 2) + wv;           // 0..255
  for (int j = 0; j < 4; ++j) {
    const int row = (j << 8) + w;                 // 0..1023
    const float* p = C + ((size_t)row << 9) + (ln << 3);
    f32x4 a = *(const f32x4*)p;
    f32x4 b = *(const f32x4*)(p + 4);
    float sq = a[0]*a[0] + a[1]*a[1] + a[2]*a[2] + a[3]*a[3]
             + b[0]*b[0] + b[1]*b[1] + b[2]*b[2] + b[3]*b[3];
    float sm = a[0] + a[1] + a[2] + a[3] + b[0] + b[1] + b[2] + b[3];
    #pragma unroll
    for (int mask = 1; mask <= 32; mask <<= 1) {
      sq += __shfl_xor(sq, mask);
      sm += __shfl_xor(sm, mask);
    }
    if (ln == 0) cterm[row] = sq + (2.0f * EPS) * sm;
  }
}

// ---------------- kernel 2: fused GEMM + argmin + segment atomics ----------------
// 4 waves; each wave owns 32 complete embedding rows and ALL 128 centroid
// columns of the K-tile (acc[2][8]) so the argmin is complete per row
// before atomics. (Round-1 bug: 64x64 wave tiles split the argmin across
// two waves -> every embedding double-counted.)
#define BN 128
#define ESTR 520   // shorts per E row (512 + 8 pad -> 1040B stride, bank-uniform)
#define CSTR 40    // shorts per C-chunk row (32 + 8 pad -> 80B stride, bank-uniform)

__global__ __launch_bounds__(256, 1) void assign_kernel(
    const float* __restrict__ E, const float* __restrict__ C,
    const float* __restrict__ cterm, float* __restrict__ sums,
    float* __restrict__ counts, int* __restrict__ maxs) {

  __shared__ __align__(16) unsigned short eTile[BN * ESTR];        // 130 KB
  __shared__ __align__(16) unsigned short cChunk[2][128 * CSTR];   // 20 KB
  __shared__ float esqS[BN], esumS[BN];

  const int tid = threadIdx.x;
  const int wv = tid >> 6, ln = tid & 63;
  const int g  = ln >> 4, cc = ln & 15;
  const int wn0 = wv << 5;          // wave row offset: 0,32,64,96

  // ---- stage embedding tile (fp32 -> bf16), perfectly coalesced ----
  const float* Eb = E + (size_t)blockIdx.x * (BN * 512);
  #pragma unroll 2
  for (int i = 0; i < 32; ++i) {
    const int f = ((i << 8) + tid) << 3;      // flat float index (8 floats/thread/iter)
    const int row = f >> 9, col = f & 511;
    const float* p = Eb + ((size_t)row << 9) + col;
    f32x4 v0 = *(const f32x4*)p;
    f32x4 v1 = *(const f32x4*)(p + 4);
    *(uint4*)&eTile[row * ESTR + col] = pack8(v0, v1);
  }
  __syncthreads();

  // ---- per-row esq / esum from the staged (bf16) tile ----
  {
    const int row = tid >> 1, half = tid & 1;
    const unsigned short* rp = &eTile[row * ESTR + (half << 8)];
    float sq = 0.f, sm = 0.f;
    for (int j = 0; j < 32; ++j) {
      uint4 raw = *(const uint4*)(rp + (j << 3));
      const unsigned short* s = (const unsigned short*)&raw;
      #pragma unroll
      for (int e = 0; e < 8; ++e) { float fv = bf2f(s[e]); sq = fmaf(fv, fv, sq); sm += fv; }
    }
    sq += __shfl_xor(sq, 1);
    sm += __shfl_xor(sm, 1);
    if (!half) { esqS[row] = sq; esumS[row] = sm; }
  }
  __syncthreads();

  float runval[8];
  int   runidx[8];
  #pragma unroll
  for (int i = 0; i < 8; ++i) { runval[i] = INFINITY; runidx[i] = 0; }

  const int crow = tid >> 1;     // staging row 0..127
  const int chalf = tid & 1;

  for (int kt = 0; kt < 8; ++kt) {
    const int kbase = kt << 7;
    f32x4 acc[2][8];
    #pragma unroll
    for (int m = 0; m < 2; ++m)
      #pragma unroll
      for (int n = 0; n < 8; ++n)
        acc[m][n] = f32x4{0.f, 0.f, 0.f, 0.f};

    // prologue: stage d=0 chunk into buffer 0
    {
      const float* p = C + ((size_t)(kbase + crow) << 9) + (chalf << 4);
      f32x4 l0 = *(const f32x4*)p;       f32x4 l1 = *(const f32x4*)(p + 4);
      f32x4 l2 = *(const f32x4*)(p + 8); f32x4 l3 = *(const f32x4*)(p + 12);
      unsigned short* w = &cChunk[0][crow * CSTR + (chalf << 4)];
      *(uint4*)w = pack8(l0, l1);
      *(uint4*)(w + 8) = pack8(l2, l3);
    }
    __syncthreads();

    for (int ds = 0; ds < 16; ++ds) {
      const int cur = ds & 1;
      f32x4 l0, l1, l2, l3;
      if (ds < 15) {   // issue next chunk's global loads early
        const float* p = C + ((size_t)(kbase + crow) << 9) + ((ds + 1) << 5) + (chalf << 4);
        l0 = *(const f32x4*)p;       l1 = *(const f32x4*)(p + 4);
        l2 = *(const f32x4*)(p + 8); l3 = *(const f32x4*)(p + 12);
      }
      s16x8 af[2], bfr[8];
      #pragma unroll
      for (int m = 0; m < 2; ++m)
        af[m] = *(const s16x8*)&eTile[(wn0 + (m << 4) + cc) * ESTR + (ds << 5) + (g << 3)];
      #pragma unroll
      for (int n = 0; n < 8; ++n)
        bfr[n] = *(const s16x8*)&cChunk[cur][((n << 4) + cc) * CSTR + (g << 3)];
      #pragma unroll
      for (int m = 0; m < 2; ++m)
        #pragma unroll
        for (int n = 0; n < 8; ++n)
          acc[m][n] = __builtin_amdgcn_mfma_f32_16x16x32_bf16(af[m], bfr[n], acc[m][n], 0, 0, 0);
      if (ds < 15) {   // write next chunk into the other buffer
        unsigned short* w = &cChunk[cur ^ 1][crow * CSTR + (chalf << 4)];
        *(uint4*)w = pack8(l0, l1);
        *(uint4*)(w + 8) = pack8(l2, l3);
      }
      __syncthreads();
    }

    // per-K-tile epilogue: fold into running (min score, argmin)
    #pragma unroll
    for (int n = 0; n < 8; ++n) {
      const int k = kbase + (n << 4) + cc;
      const float ct = cterm[k];
      #pragma unroll
      for (int m = 0; m < 2; ++m)
        #pragma unroll
        for (int r = 0; r < 4; ++r) {
          const float v = fmaf(-2.f, acc[m][n][r], ct);
          const int idx = (m << 2) + r;
          if (v < runval[idx]) { runval[idx] = v; runidx[idx] = k; }
        }
    }
  }

  // ---- final: cross-lane argmin reduce + segment atomics ----
  #pragma unroll
  for (int m = 0; m < 2; ++m)
    #pragma unroll
    for (int r = 0; r < 4; ++r) {
      float v = runval[(m << 2) + r];
      int idx = runidx[(m << 2) + r];
      #pragma unroll
      for (int mask = 1; mask <= 8; mask <<= 1) {
        float pv = __shfl_xor(v, mask);
        int   pi = __shfl_xor(idx, mask);
        if (pv < v || (pv == v && pi < idx)) { v = pv; idx = pi; }
      }
      if (cc == 0) {
        const int nloc = wn0 + (m << 4) + (g << 2) + r;
        const float sq = v + esqS[nloc] - (2.f * EPS) * esumS[nloc] + 512.f * EPS * EPS;
        const float d = sqrtf(fmaxf(sq, 0.f));
        atomicAdd(&sums[idx], d);
        atomicAdd(&counts[idx], 1.f);
        atomicMax(&maxs[idx], __float_as_int(d));
      }
    }
}

// ---------------- kernel 3: final reduction over K=1024 clusters ----------------
__global__ __launch_bounds__(1024) void finalize(const float* __restrict__ sums,
                                                 const float* __restrict__ counts,
                                                 const int* __restrict__ maxs,
                                                 float* __restrict__ out) {
  const int t = threadIdx.x;
  const float cnt = counts[t];
  const float s = sums[t];
  const float mx = fmaxf(__int_as_float(maxs[t]), 0.f);
  float v0 = s / (cnt + 1.0f);
  float v1 = mx;
  float v2 = cnt;
  #pragma unroll
  for (int mask = 1; mask <= 32; mask <<= 1) {
    v0 += __shfl_xor(v0, mask);
    v1 += __shfl_xor(v1, mask);
    v2 += __shfl_xor(v2, mask);
  }
  __shared__ float r0[16], r1[16], r2[16];
  const int wv = t >> 6, ln = t & 63;
  if (ln == 0) { r0[wv] = v0; r1[wv] = v1; r2[wv] = v2; }
  __syncthreads();
  if (t == 0) {
    float a = 0.f, b = 0.f, c = 0.f;
    for (int i = 0; i < 16; ++i) { a += r0[i]; b += r1[i]; c += r2[i]; }
    out[0] = a * (1.f / 1024.f);
    out[1] = b * (1.f / 1024.f);
    out[2] = c * (1.f / 1024.f);
  }
}

extern "C" void kernel_launch(void* const* d_in, const int* in_sizes, int n_in,
                              void* d_out, int out_size, void* d_ws, size_t ws_size,
                              hipStream_t stream) {
  const float* E = (const float*)d_in[0];   // (65536, 512)
  const float* C = (const float*)d_in[1];   // (1024, 512)
  float* out = (float*)d_out;               // 3 floats

  float* cterm  = (float*)d_ws;             // 1024
  float* sums   = cterm + 1024;             // 1024
  float* counts = sums + 1024;              // 1024
  int*   maxs   = (int*)(counts + 1024);    // 1024

  hipMemsetAsync(sums, 0, 3 * 1024 * sizeof(float), stream);  // sums, counts, maxs
  centroid_stats<<<64, 256, 0, stream>>>(C, cterm);
  assign_kernel<<<512, 256, 0, stream>>>(E, C, cterm, sums, counts, maxs);
  finalize<<<1, 1024, 0, stream>>>(sums, counts, maxs, out);
}

// Round 3
// 300.947 us; speedup vs baseline: 1.3687x; 1.3687x over previous
//
#include <hip/hip_runtime.h>
#include <hip/hip_bf16.h>

#define EPS 1e-6f

typedef float f32x4 __attribute__((ext_vector_type(4)));
typedef short s16x8 __attribute__((ext_vector_type(8)));

static __device__ __forceinline__ unsigned cvt2u(float x, float y) {
  __hip_bfloat162 h = __float22bfloat162_rn(make_float2(x, y));
  union { __hip_bfloat162 h; unsigned u; } c; c.h = h; return c.u;
}
static __device__ __forceinline__ uint4 pack8(const f32x4 a, const f32x4 b) {
  uint4 r; r.x = cvt2u(a[0], a[1]); r.y = cvt2u(a[2], a[3]);
  r.z = cvt2u(b[0], b[1]); r.w = cvt2u(b[2], b[3]); return r;
}
static __device__ __forceinline__ float bf2f(unsigned short u) {
  union { unsigned u; float f; } c; c.u = ((unsigned)u) << 16; return c.f;
}

// XOR-swizzled byte offsets (both write and read sides use the same map).
// eTile: [128][512] bf16, row stride 1024B.  cTile: [256][32] bf16, row stride 64B.
#define SWZE(row, off) ((((row) << 10) + (off)) ^ (((row) & 7) << 4))
#define SWZC(row, off) ((((row) << 6)  + (off)) ^ (((row) & 7) << 4))

// ---------------- kernel 1: C -> bf16 copy + per-centroid csq + 2*eps*csum ----------------
__global__ __launch_bounds__(256) void prep_centroids(const float* __restrict__ C,
                                                      unsigned short* __restrict__ cbf,
                                                      float* __restrict__ cterm) {
  const int wv = threadIdx.x >> 6, ln = threadIdx.x & 63;
  const int w = (blockIdx.x << 2) + wv;             // 0..255
  for (int j = 0; j < 4; ++j) {
    const int row = (j << 8) + w;                   // 0..1023
    const float* p = C + ((size_t)row << 9) + (ln << 3);
    f32x4 a = *(const f32x4*)p;
    f32x4 b = *(const f32x4*)(p + 4);
    *(uint4*)&cbf[((size_t)row << 9) + (ln << 3)] = pack8(a, b);
    float sq = a[0]*a[0] + a[1]*a[1] + a[2]*a[2] + a[3]*a[3]
             + b[0]*b[0] + b[1]*b[1] + b[2]*b[2] + b[3]*b[3];
    float sm = a[0] + a[1] + a[2] + a[3] + b[0] + b[1] + b[2] + b[3];
    #pragma unroll
    for (int mask = 1; mask <= 32; mask <<= 1) {
      sq += __shfl_xor(sq, mask);
      sm += __shfl_xor(sm, mask);
    }
    if (ln == 0) cterm[row] = sq + (2.0f * EPS) * sm;
  }
}

// ---------------- kernel 2: fused GEMM + argmin + segment atomics ----------------
// 512 threads / 8 waves. Block owns 128 embedding rows; K-tile = 256 centroids.
// Wave (wr,wc): wr=wv>>2 row-half (64 rows), wc=wv&3 col-block (64 centroids).
// acc[4][4] of 16x16x32 MFMAs (16 MFMA per 8 fragment reads).
// E staged to LDS in bf16 incrementally during kt=0 (32-dim chunks, overlaps HBM
// with compute); C chunk [256][32] single-buffered, reg-prefetched one step ahead.
// Cross-wave (col-split) argmin combined at the end via a small LDS buffer that
// aliases the C chunk, then one atomic triple per embedding row.
__global__ __launch_bounds__(512, 2) void assign_kernel(
    const float* __restrict__ E, const unsigned short* __restrict__ cbf,
    const float* __restrict__ cterm, float* __restrict__ sums,
    float* __restrict__ counts, int* __restrict__ maxs) {

  __shared__ __align__(16) unsigned char smem[147456];
  unsigned char* eB = smem;                      // 131072 B: eTile
  unsigned char* cB = smem + 131072;             // 16384 B: cTile
  float2* cmb = (float2*)(smem + 131072);        // [128][4] alias, used post-compute

  const int tid = threadIdx.x;
  const int wv = tid >> 6, ln = tid & 63;
  const int g = ln >> 4, cc = ln & 15;
  const int row0 = (wv >> 2) << 6;               // 0 / 64
  const int col0 = (wv & 3) << 6;                // 0 / 64 / 128 / 192

  const int erow = tid >> 2, eq = tid & 3;       // E staging: row 0..127, quarter
  const int crow = tid >> 1, ch = tid & 1;       // C staging: row 0..255, half

  const float* Eb = E + ((size_t)blockIdx.x << 16);   // 128*512 floats

  float runval[16]; int runidx[16];
  #pragma unroll
  for (int i = 0; i < 16; ++i) { runval[i] = INFINITY; runidx[i] = 0; }

  // initial staged loads (kt=0, ds=0)
  f32x4 e0, e1; uint4 c0, c1;
  {
    const float* p = Eb + ((size_t)erow << 9) + (eq << 3);
    e0 = *(const f32x4*)p; e1 = *(const f32x4*)(p + 4);
    const unsigned short* q = cbf + ((size_t)crow << 9) + (ch << 4);
    c0 = *(const uint4*)q; c1 = *(const uint4*)(q + 8);
  }

  for (int kt = 0; kt < 4; ++kt) {
    f32x4 acc[4][4];
    #pragma unroll
    for (int m = 0; m < 4; ++m)
      #pragma unroll
      for (int n = 0; n < 4; ++n) acc[m][n] = f32x4{0.f, 0.f, 0.f, 0.f};

    for (int ds = 0; ds < 16; ++ds) {
      __syncthreads();                       // previous step's LDS reads done
      if (kt == 0)
        *(uint4*)(eB + SWZE(erow, (ds << 6) + (eq << 4))) = pack8(e0, e1);
      *(uint4*)(cB + SWZC(crow, (ch << 5)))      = c0;
      *(uint4*)(cB + SWZC(crow, (ch << 5) + 16)) = c1;
      {
        int nds = ds + 1, nkt = kt;
        if (nds == 16) { nds = 0; nkt = kt + 1; }
        if (nkt < 4) {
          const unsigned short* q =
              cbf + (((size_t)(nkt << 8) + crow) << 9) + (nds << 5) + (ch << 4);
          c0 = *(const uint4*)q; c1 = *(const uint4*)(q + 8);
        }
        if (kt == 0 && ds < 15) {
          const float* p = Eb + ((size_t)erow << 9) + ((ds + 1) << 5) + (eq << 3);
          e0 = *(const f32x4*)p; e1 = *(const f32x4*)(p + 4);
        }
      }
      __syncthreads();                       // staged chunk visible
      s16x8 af[4], bfr[4];
      #pragma unroll
      for (int m = 0; m < 4; ++m) {
        const int r = row0 + (m << 4) + cc;
        af[m] = *(const s16x8*)(eB + SWZE(r, (ds << 6) + (g << 4)));
      }
      #pragma unroll
      for (int n = 0; n < 4; ++n) {
        const int r = col0 + (n << 4) + cc;
        bfr[n] = *(const s16x8*)(cB + SWZC(r, (g << 4)));
      }
      #pragma unroll
      for (int m = 0; m < 4; ++m)
        #pragma unroll
        for (int n = 0; n < 4; ++n)
          acc[m][n] = __builtin_amdgcn_mfma_f32_16x16x32_bf16(af[m], bfr[n], acc[m][n], 0, 0, 0);
    }

    // fold this K-tile into the running per-lane argmin (k ascending -> first-min kept)
    #pragma unroll
    for (int n = 0; n < 4; ++n) {
      const int k = (kt << 8) + col0 + (n << 4) + cc;
      const float ct = cterm[k];
      #pragma unroll
      for (int m = 0; m < 4; ++m)
        #pragma unroll
        for (int r = 0; r < 4; ++r) {
          const float v = fmaf(-2.f, acc[m][n][r], ct);
          const int idx = (m << 2) + r;
          if (v < runval[idx]) { runval[idx] = v; runidx[idx] = k; }
        }
    }
  }

  // cross-lane argmin over cc (16 lanes share a row)
  #pragma unroll
  for (int i = 0; i < 16; ++i) {
    float v = runval[i]; int idx = runidx[i];
    #pragma unroll
    for (int mask = 1; mask <= 8; mask <<= 1) {
      float pv = __shfl_xor(v, mask);
      int   pi = __shfl_xor(idx, mask);
      if (pv < v || (pv == v && pi < idx)) { v = pv; idx = pi; }
    }
    runval[i] = v; runidx[i] = idx;
  }

  __syncthreads();                            // all waves done reading cB
  if (cc == 0) {
    #pragma unroll
    for (int m = 0; m < 4; ++m)
      #pragma unroll
      for (int r = 0; r < 4; ++r) {
        const int rl = row0 + (m << 4) + (g << 2) + r;
        cmb[(rl << 2) + (wv & 3)] =
            make_float2(runval[(m << 2) + r], __int_as_float(runidx[(m << 2) + r]));
      }
  }
  __syncthreads();

  // combine 4 col-waves per row + per-row esq/esum from staged tile + atomics
  {
    const int row = tid >> 2, q = tid & 3;
    float2 me = cmb[(row << 2) + q];
    float v = me.x; int idx = __float_as_int(me.y);
    float sq = 0.f, sm = 0.f;
    #pragma unroll 4
    for (int j = 0; j < 16; ++j) {
      uint4 raw = *(const uint4*)(eB + SWZE(row, (q << 8) + (j << 4)));
      const unsigned short* s = (const unsigned short*)&raw;
      #pragma unroll
      for (int e = 0; e < 8; ++e) { float fv = bf2f(s[e]); sq = fmaf(fv, fv, sq); sm += fv; }
    }
    #pragma unroll
    for (int mask = 1; mask <= 2; mask <<= 1) {
      sq += __shfl_xor(sq, mask);
      sm += __shfl_xor(sm, mask);
      float pv = __shfl_xor(v, mask);
      int   pi = __shfl_xor(idx, mask);
      if (pv < v || (pv == v && pi < idx)) { v = pv; idx = pi; }
    }
    if (q == 0) {
      const float sqd = v + sq - (2.f * EPS) * sm + 512.f * EPS * EPS;
      const float d = sqrtf(fmaxf(sqd, 0.f));
      atomicAdd(&sums[idx], d);
      atomicAdd(&counts[idx], 1.f);
      atomicMax(&maxs[idx], __float_as_int(d));
    }
  }
}

// ---------------- kernel 3: final reduction over K=1024 clusters ----------------
__global__ __launch_bounds__(1024) void finalize(const float* __restrict__ sums,
                                                 const float* __restrict__ counts,
                                                 const int* __restrict__ maxs,
                                                 float* __restrict__ out) {
  const int t = threadIdx.x;
  const float cnt = counts[t];
  const float s = sums[t];
  const float mx = fmaxf(__int_as_float(maxs[t]), 0.f);
  float v0 = s / (cnt + 1.0f);
  float v1 = mx;
  float v2 = cnt;
  #pragma unroll
  for (int mask = 1; mask <= 32; mask <<= 1) {
    v0 += __shfl_xor(v0, mask);
    v1 += __shfl_xor(v1, mask);
    v2 += __shfl_xor(v2, mask);
  }
  __shared__ float r0[16], r1[16], r2[16];
  const int wv = t >> 6, ln = t & 63;
  if (ln == 0) { r0[wv] = v0; r1[wv] = v1; r2[wv] = v2; }
  __syncthreads();
  if (t == 0) {
    float a = 0.f, b = 0.f, c = 0.f;
    for (int i = 0; i < 16; ++i) { a += r0[i]; b += r1[i]; c += r2[i]; }
    out[0] = a * (1.f / 1024.f);
    out[1] = b * (1.f / 1024.f);
    out[2] = c * (1.f / 1024.f);
  }
}

extern "C" void kernel_launch(void* const* d_in, const int* in_sizes, int n_in,
                              void* d_out, int out_size, void* d_ws, size_t ws_size,
                              hipStream_t stream) {
  const float* E = (const float*)d_in[0];   // (65536, 512)
  const float* C = (const float*)d_in[1];   // (1024, 512)
  float* out = (float*)d_out;               // 3 floats

  unsigned short* cbf = (unsigned short*)d_ws;        // 1024*512 bf16 = 1 MB
  float* cterm  = (float*)((char*)d_ws + (1 << 20));  // 1024
  float* sums   = cterm + 1024;                       // 1024
  float* counts = sums + 1024;                        // 1024
  int*   maxs   = (int*)(counts + 1024);              // 1024

  hipMemsetAsync(sums, 0, 3 * 1024 * sizeof(float), stream);  // sums, counts, maxs
  prep_centroids<<<64, 256, 0, stream>>>(C, cbf, cterm);
  assign_kernel<<<512, 512, 0, stream>>>(E, cbf, cterm, sums, counts, maxs);
  finalize<<<1, 1024, 0, stream>>>(sums, counts, maxs, out);
}

// Round 4
// 295.387 us; speedup vs baseline: 1.3944x; 1.0188x over previous
//
#include <hip/hip_runtime.h>
#include <hip/hip_bf16.h>

#define EPS 1e-6f

typedef float f32x4 __attribute__((ext_vector_type(4)));
typedef short s16x8 __attribute__((ext_vector_type(8)));

static __device__ __forceinline__ unsigned cvt2u(float x, float y) {
  __hip_bfloat162 h = __float22bfloat162_rn(make_float2(x, y));
  union { __hip_bfloat162 h; unsigned u; } c; c.h = h; return c.u;
}
static __device__ __forceinline__ uint4 pack8(const f32x4 a, const f32x4 b) {
  uint4 r; r.x = cvt2u(a[0], a[1]); r.y = cvt2u(a[2], a[3]);
  r.z = cvt2u(b[0], b[1]); r.w = cvt2u(b[2], b[3]); return r;
}
static __device__ __forceinline__ float bf2f(unsigned short u) {
  union { unsigned u; float f; } c; c.u = ((unsigned)u) << 16; return c.f;
}

// XOR-swizzled byte offsets. eTile: [128][512] bf16 (1024B row stride).
// cTile: [256][64] bf16 (128B row stride).
#define SWZE(row, off) ((((row) << 10) + (off)) ^ (((row) & 7) << 4))
#define SWZC(row, off) ((((row) << 7)  + (off)) ^ (((row) & 7) << 4))

// ---------------- kernel 1: C -> bf16 copy + per-centroid csq + 2*eps*csum ----------------
__global__ __launch_bounds__(256) void prep_centroids(const float* __restrict__ C,
                                                      unsigned short* __restrict__ cbf,
                                                      float* __restrict__ cterm) {
  const int wv = threadIdx.x >> 6, ln = threadIdx.x & 63;
  const int row = (blockIdx.x << 2) + wv;           // 0..1023 (grid 256)
  const float* p = C + ((size_t)row << 9) + (ln << 3);
  f32x4 a = *(const f32x4*)p;
  f32x4 b = *(const f32x4*)(p + 4);
  *(uint4*)&cbf[((size_t)row << 9) + (ln << 3)] = pack8(a, b);
  float sq = a[0]*a[0] + a[1]*a[1] + a[2]*a[2] + a[3]*a[3]
           + b[0]*b[0] + b[1]*b[1] + b[2]*b[2] + b[3]*b[3];
  float sm = a[0] + a[1] + a[2] + a[3] + b[0] + b[1] + b[2] + b[3];
  #pragma unroll
  for (int mask = 1; mask <= 32; mask <<= 1) {
    sq += __shfl_xor(sq, mask);
    sm += __shfl_xor(sm, mask);
  }
  if (ln == 0) cterm[row] = sq + (2.0f * EPS) * sm;
}

// ---------------- kernel 2: fused GEMM + argmin + segment atomics ----------------
// 512 threads / 8 waves; block = 128 embedding rows x K-tile of 256 centroids.
// Wave (wv>>2, wv&3): 64-row half x 64-col quarter, acc[4][4] of 16x16x32.
// eTile [128][512] bf16 resident (staged during kt=0); cChunk [256][64] bf16
// re-staged per 64-dim step. Schedule per step:
//   barrier A (drains prev prefetch, already landed) -> ds_write staged chunk
//   -> barrier B (lgkm only) -> ISSUE next global prefetch -> frag reads + MFMA.
// (Round-3 bug: prefetch was issued BETWEEN the barriers, so barrier B's
// implicit vmcnt(0) drained a just-issued L2/HBM load every step.)
__global__ __launch_bounds__(512, 2) void assign_kernel(
    const float* __restrict__ E, const unsigned short* __restrict__ cbf,
    const float* __restrict__ cterm, float* __restrict__ sums,
    float* __restrict__ counts, int* __restrict__ maxs) {

  __shared__ __align__(16) unsigned char smem[163840];   // exactly 160 KiB
  unsigned char* eB = smem;                      // 131072 B
  unsigned char* cB = smem + 131072;             // 32768 B
  float2* cmb = (float2*)(smem + 131072);        // [128][4] alias, post-compute only

  const int tid = threadIdx.x;
  const int wv = tid >> 6, ln = tid & 63;
  const int g = ln >> 4, cc = ln & 15;
  const int row0 = (wv >> 2) << 6;               // 0 / 64
  const int col0 = (wv & 3) << 6;                // 0 / 64 / 128 / 192

  const int erow = tid >> 2, eq = tid & 3;       // E staging: 16 floats/thread
  const int crow = tid >> 1, ch = tid & 1;       // C staging: 32 bf16/thread

  const float* Eb = E + ((size_t)blockIdx.x << 16);

  float runval[16]; int runidx[16];
  #pragma unroll
  for (int i = 0; i < 16; ++i) { runval[i] = INFINITY; runidx[i] = 0; }

  f32x4 e0, e1, e2, e3; uint4 c0, c1, c2, c3;
  {  // prologue prefetch: chunk sds=0
    const float* p = Eb + ((size_t)erow << 9) + (eq << 4);
    e0 = *(const f32x4*)p;       e1 = *(const f32x4*)(p + 4);
    e2 = *(const f32x4*)(p + 8); e3 = *(const f32x4*)(p + 12);
    const unsigned short* q = cbf + ((size_t)crow << 9) + (ch << 5);
    c0 = *(const uint4*)q;        c1 = *(const uint4*)(q + 8);
    c2 = *(const uint4*)(q + 16); c3 = *(const uint4*)(q + 24);
  }

  f32x4 acc[4][4];
  for (int sds = 0; sds < 32; ++sds) {
    const int kt = sds >> 3, ds = sds & 7;
    if (ds == 0) {
      #pragma unroll
      for (int m = 0; m < 4; ++m)
        #pragma unroll
        for (int n = 0; n < 4; ++n) acc[m][n] = f32x4{0.f, 0.f, 0.f, 0.f};
    }

    __syncthreads();                       // A: prev step's frag reads done
    if (kt == 0) {
      *(uint4*)(eB + SWZE(erow, (ds << 7) + (eq << 5)))      = pack8(e0, e1);
      *(uint4*)(eB + SWZE(erow, (ds << 7) + (eq << 5) + 16)) = pack8(e2, e3);
    }
    {
      unsigned char* w0 = cB + SWZC(crow, (ch << 6));
      unsigned char* w1 = cB + SWZC(crow, (ch << 6) + 16);
      unsigned char* w2 = cB + SWZC(crow, (ch << 6) + 32);
      unsigned char* w3 = cB + SWZC(crow, (ch << 6) + 48);
      *(uint4*)w0 = c0; *(uint4*)w1 = c1; *(uint4*)w2 = c2; *(uint4*)w3 = c3;
    }
    __syncthreads();                       // B: staged chunk visible (lgkm-only drain)

    // issue NEXT prefetch now -> flies across the MFMA phase below
    if (sds < 31) {
      const int nsds = sds + 1, nkt = nsds >> 3, nds = nsds & 7;
      const unsigned short* q =
          cbf + (((size_t)(nkt << 8) + crow) << 9) + (nds << 6) + (ch << 5);
      c0 = *(const uint4*)q;        c1 = *(const uint4*)(q + 8);
      c2 = *(const uint4*)(q + 16); c3 = *(const uint4*)(q + 24);
      if (nkt == 0) {
        const float* p = Eb + ((size_t)erow << 9) + (nds << 6) + (eq << 4);
        e0 = *(const f32x4*)p;       e1 = *(const f32x4*)(p + 4);
        e2 = *(const f32x4*)(p + 8); e3 = *(const f32x4*)(p + 12);
      }
    }

    #pragma unroll
    for (int kk = 0; kk < 2; ++kk) {
      s16x8 af[4], bfr[4];
      #pragma unroll
      for (int m = 0; m < 4; ++m) {
        const int r = row0 + (m << 4) + cc;
        af[m] = *(const s16x8*)(eB + SWZE(r, (ds << 7) + (kk << 6) + (g << 4)));
      }
      #pragma unroll
      for (int n = 0; n < 4; ++n) {
        const int r = col0 + (n << 4) + cc;
        bfr[n] = *(const s16x8*)(cB + SWZC(r, (kk << 6) + (g << 4)));
      }
      #pragma unroll
      for (int m = 0; m < 4; ++m)
        #pragma unroll
        for (int n = 0; n < 4; ++n)
          acc[m][n] = __builtin_amdgcn_mfma_f32_16x16x32_bf16(af[m], bfr[n], acc[m][n], 0, 0, 0);
    }

    if (ds == 7) {   // fold this K-tile into running argmin (k ascending)
      #pragma unroll
      for (int n = 0; n < 4; ++n) {
        const int k = (kt << 8) + col0 + (n << 4) + cc;
        const float ct = cterm[k];
        #pragma unroll
        for (int m = 0; m < 4; ++m)
          #pragma unroll
          for (int r = 0; r < 4; ++r) {
            const float v = fmaf(-2.f, acc[m][n][r], ct);
            const int idx = (m << 2) + r;
            if (v < runval[idx]) { runval[idx] = v; runidx[idx] = k; }
          }
      }
    }
  }

  // cross-lane argmin over cc (16 lanes share a row)
  #pragma unroll
  for (int i = 0; i < 16; ++i) {
    float v = runval[i]; int idx = runidx[i];
    #pragma unroll
    for (int mask = 1; mask <= 8; mask <<= 1) {
      float pv = __shfl_xor(v, mask);
      int   pi = __shfl_xor(idx, mask);
      if (pv < v || (pv == v && pi < idx)) { v = pv; idx = pi; }
    }
    runval[i] = v; runidx[i] = idx;
  }

  __syncthreads();                            // all waves done with cB
  if (cc == 0) {
    #pragma unroll
    for (int m = 0; m < 4; ++m)
      #pragma unroll
      for (int r = 0; r < 4; ++r) {
        const int rl = row0 + (m << 4) + (g << 2) + r;
        cmb[(rl << 2) + (wv & 3)] =
            make_float2(runval[(m << 2) + r], __int_as_float(runidx[(m << 2) + r]));
      }
  }
  __syncthreads();

  // combine 4 col-waves per row + per-row esq/esum from staged tile + atomics
  {
    const int row = tid >> 2, q = tid & 3;
    float2 me = cmb[(row << 2) + q];
    float v = me.x; int idx = __float_as_int(me.y);
    float sq = 0.f, sm = 0.f;
    #pragma unroll 4
    for (int j = 0; j < 16; ++j) {
      uint4 raw = *(const uint4*)(eB + SWZE(row, (q << 8) + (j << 4)));
      const unsigned short* s = (const unsigned short*)&raw;
      #pragma unroll
      for (int e = 0; e < 8; ++e) { float fv = bf2f(s[e]); sq = fmaf(fv, fv, sq); sm += fv; }
    }
    #pragma unroll
    for (int mask = 1; mask <= 2; mask <<= 1) {
      sq += __shfl_xor(sq, mask);
      sm += __shfl_xor(sm, mask);
      float pv = __shfl_xor(v, mask);
      int   pi = __shfl_xor(idx, mask);
      if (pv < v || (pv == v && pi < idx)) { v = pv; idx = pi; }
    }
    if (q == 0) {
      const float sqd = v + sq - (2.f * EPS) * sm + 512.f * EPS * EPS;
      const float d = sqrtf(fmaxf(sqd, 0.f));
      atomicAdd(&sums[idx], d);
      atomicAdd(&counts[idx], 1.f);
      atomicMax(&maxs[idx], __float_as_int(d));
    }
  }
}

// ---------------- kernel 3: final reduction over K=1024 clusters ----------------
__global__ __launch_bounds__(1024) void finalize(const float* __restrict__ sums,
                                                 const float* __restrict__ counts,
                                                 const int* __restrict__ maxs,
                                                 float* __restrict__ out) {
  const int t = threadIdx.x;
  const float cnt = counts[t];
  const float s = sums[t];
  const float mx = fmaxf(__int_as_float(maxs[t]), 0.f);
  float v0 = s / (cnt + 1.0f);
  float v1 = mx;
  float v2 = cnt;
  #pragma unroll
  for (int mask = 1; mask <= 32; mask <<= 1) {
    v0 += __shfl_xor(v0, mask);
    v1 += __shfl_xor(v1, mask);
    v2 += __shfl_xor(v2, mask);
  }
  __shared__ float r0[16], r1[16], r2[16];
  const int wv = t >> 6, ln = t & 63;
  if (ln == 0) { r0[wv] = v0; r1[wv] = v1; r2[wv] = v2; }
  __syncthreads();
  if (t == 0) {
    float a = 0.f, b = 0.f, c = 0.f;
    for (int i = 0; i < 16; ++i) { a += r0[i]; b += r1[i]; c += r2[i]; }
    out[0] = a * (1.f / 1024.f);
    out[1] = b * (1.f / 1024.f);
    out[2] = c * (1.f / 1024.f);
  }
}

extern "C" void kernel_launch(void* const* d_in, const int* in_sizes, int n_in,
                              void* d_out, int out_size, void* d_ws, size_t ws_size,
                              hipStream_t stream) {
  const float* E = (const float*)d_in[0];   // (65536, 512)
  const float* C = (const float*)d_in[1];   // (1024, 512)
  float* out = (float*)d_out;               // 3 floats

  unsigned short* cbf = (unsigned short*)d_ws;        // 1024*512 bf16 = 1 MB
  float* cterm  = (float*)((char*)d_ws + (1 << 20));  // 1024
  float* sums   = cterm + 1024;                       // 1024
  float* counts = sums + 1024;                        // 1024
  int*   maxs   = (int*)(counts + 1024);              // 1024

  hipMemsetAsync(sums, 0, 3 * 1024 * sizeof(float), stream);  // sums, counts, maxs
  prep_centroids<<<256, 256, 0, stream>>>(C, cbf, cterm);
  assign_kernel<<<512, 512, 0, stream>>>(E, cbf, cterm, sums, counts, maxs);
  finalize<<<1, 1024, 0, stream>>>(sums, counts, maxs, out);
}